// Round 4
// baseline (121.037 us; speedup 1.0000x reference)
//
#include <hip/hip_runtime.h>
#include <math.h>
#include <stdint.h>

#define IN_DIM  256
#define OUT_DIM 256
#define NROWS   68     // G + K
#define NT      71     // knot count
#define BATCH   512
#define W_ELEMS (NROWS * IN_DIM * OUT_DIM)   // 4,456,448

// ---- Kernel A: convert w fp32 -> packed bf16 pairs in d_ws ----
__device__ __forceinline__ uint32_t bf16_rne(float f) {
  uint32_t u = __builtin_bit_cast(uint32_t, f);
  return (u + 0x7fffu + ((u >> 16) & 1u)) >> 16;   // finite inputs only
}

__global__ __launch_bounds__(256) void cvt_kernel(const float* __restrict__ w,
                                                  uint32_t* __restrict__ wb) {
  const int base = (blockIdx.x * 256 + threadIdx.x) * 8;   // 8 floats / thread
  const float4 a = *(const float4*)(w + base);
  const float4 b = *(const float4*)(w + base + 4);
  uint4 o;
  o.x = bf16_rne(a.x) | (bf16_rne(a.y) << 16);
  o.y = bf16_rne(a.z) | (bf16_rne(a.w) << 16);
  o.z = bf16_rne(b.x) | (bf16_rne(b.y) << 16);
  o.w = bf16_rne(b.z) | (bf16_rne(b.w) << 16);
  *(uint4*)(wb + base / 2) = o;
}

// ---- Kernel B: gather-accumulate, bf16 weights, 2-deep SW pipeline ----
__device__ __forceinline__ void fma8(const uint4 q, const float y, float* acc) {
  acc[0] += y * __builtin_bit_cast(float, q.x << 16);
  acc[1] += y * __builtin_bit_cast(float, q.x & 0xffff0000u);
  acc[2] += y * __builtin_bit_cast(float, q.y << 16);
  acc[3] += y * __builtin_bit_cast(float, q.y & 0xffff0000u);
  acc[4] += y * __builtin_bit_cast(float, q.z << 16);
  acc[5] += y * __builtin_bit_cast(float, q.z & 0xffff0000u);
  acc[6] += y * __builtin_bit_cast(float, q.w << 16);
  acc[7] += y * __builtin_bit_cast(float, q.w & 0xffff0000u);
}

__global__ __launch_bounds__(256, 6) void kan_gather_kernel(
    const float* __restrict__ x, const uint4* __restrict__ wp,
    const float* __restrict__ t, float* __restrict__ out) {
  __shared__ float  lt[NT];
  __shared__ float4 lyv[64];    // N0..N3 per local c
  __shared__ float  lys[64];    // silu(x) per local c
  __shared__ int    lbase[64];  // i-3 per local c
  __shared__ float  red[8 * 32 * 9];

  const int tid = threadIdx.x;
  const unsigned bid = blockIdx.x;
  // XCD-affine swizzle: slice = (xcd>>1); each slice's 2.2 MB bf16 region is
  // L2-resident on its XCD pair. b covers [0,512) per slice (bijective).
  const int sl = (bid & 7) >> 1;
  const int b  = ((bid & 1) << 8) | (bid >> 3);

  if (tid < NT) lt[tid] = t[tid];
  __syncthreads();

  // ---- Phase 1: basis for the block's 64 c's ----
  if (tid < 64) {
    const int c = sl * 64 + tid;
    const float xv = x[b * IN_DIM + c];
    int i = 3 + (int)floorf((xv + 1.0f) * 32.0f);
    i = i < 3 ? 3 : (i > 66 ? 66 : i);
    while (i > 3 && xv < lt[i]) --i;
    while (i < 66 && xv >= lt[i + 1]) ++i;

    float N0 = 1.f, N1 = 0.f, N2 = 0.f, N3 = 0.f;
    { // p = 1
      const float l1 = xv - lt[i];
      const float r1 = lt[i + 1] - xv;
      const float tp = N0 / (r1 + l1);
      N1 = l1 * tp; N0 = r1 * tp;
    }
    { // p = 2
      const float l1 = xv - lt[i];
      const float l2 = xv - lt[i - 1];
      const float r1 = lt[i + 1] - xv;
      const float r2 = lt[i + 2] - xv;
      float saved = 0.f;
      const float tp0 = N0 / (r1 + l2);
      const float n0 = saved + r1 * tp0; saved = l2 * tp0;
      const float tp1 = N1 / (r2 + l1);
      const float n1 = saved + r2 * tp1; saved = l1 * tp1;
      N0 = n0; N1 = n1; N2 = saved;
    }
    { // p = 3
      const float l1 = xv - lt[i];
      const float l2 = xv - lt[i - 1];
      const float l3 = xv - lt[i - 2];
      const float r1 = lt[i + 1] - xv;
      const float r2 = lt[i + 2] - xv;
      const float r3 = lt[i + 3] - xv;
      float saved = 0.f;
      const float tp0 = N0 / (r1 + l3);
      const float n0 = saved + r1 * tp0; saved = l3 * tp0;
      const float tp1 = N1 / (r2 + l2);
      const float n1 = saved + r2 * tp1; saved = l2 * tp1;
      const float tp2 = N2 / (r3 + l1);
      const float n2 = saved + r3 * tp2; saved = l1 * tp2;
      N0 = n0; N1 = n1; N2 = n2; N3 = saved;
    }
    lyv[tid]   = make_float4(N0, N1, N2, N3);
    lys[tid]   = xv / (1.0f + expf(-xv));
    lbase[tid] = i - 3;
  }
  __syncthreads();

  // ---- Phase 2: thread = (ol in [0,32) o-octet, cs in [0,8) -> 8 c's) ----
  const int ol   = tid & 31;
  const int cs   = tid >> 5;
  const int cbeg = cs * 8;
  const uint4* __restrict__ wb = wp + ol;   // + 32-bit uint4 offsets below

  float acc[8] = {0.f, 0.f, 0.f, 0.f, 0.f, 0.f, 0.f, 0.f};

  // main pass: 4 spline rows per c, 2-deep register pipeline over the 8 c's
  {
    int co = (sl * 64 + cbeg) * 32;
    int rb = lbase[cbeg];
    uint4 qa0 = wb[co + (rb + 0) * 8192];
    uint4 qa1 = wb[co + (rb + 1) * 8192];
    uint4 qa2 = wb[co + (rb + 2) * 8192];
    uint4 qa3 = wb[co + (rb + 3) * 8192];
    #pragma unroll
    for (int m = 0; m < 8; ++m) {
      uint4 qb0, qb1, qb2, qb3;
      if (m < 7) {
        const int cn = cbeg + m + 1;
        const int cn_off = (sl * 64 + cn) * 32;
        const int rn = lbase[cn];
        qb0 = wb[cn_off + (rn + 0) * 8192];
        qb1 = wb[cn_off + (rn + 1) * 8192];
        qb2 = wb[cn_off + (rn + 2) * 8192];
        qb3 = wb[cn_off + (rn + 3) * 8192];
      }
      const float4 yv = lyv[cbeg + m];
      fma8(qa0, yv.x, acc);
      fma8(qa1, yv.y, acc);
      fma8(qa2, yv.z, acc);
      fma8(qa3, yv.w, acc);
      if (m < 7) { qa0 = qb0; qa1 = qb1; qa2 = qb2; qa3 = qb3; }
    }
  }

  // silu pass: row 67 for the 8 c's — 8 independent loads, fully unrolled
  {
    uint4 s[8];
    #pragma unroll
    for (int m = 0; m < 8; ++m)
      s[m] = wb[(sl * 64 + cbeg + m) * 32 + 67 * 8192];
    #pragma unroll
    for (int m = 0; m < 8; ++m)
      fma8(s[m], lys[cbeg + m], acc);
  }

  // ---- Phase 3: reduce 8 c-sub-slices in LDS, atomicAdd into out ----
  float* r = &red[(cs * 32 + ol) * 9];
  #pragma unroll
  for (int j = 0; j < 8; ++j) r[j] = acc[j];
  __syncthreads();
  if (tid < 32) {
    float* op = out + b * OUT_DIM + ol * 8;
    #pragma unroll
    for (int j = 0; j < 8; ++j) {
      float s = 0.f;
      #pragma unroll
      for (int sI = 0; sI < 8; ++sI) s += red[(sI * 32 + ol) * 9 + j];
      atomicAdd(op + j, s);
    }
  }
}

extern "C" void kernel_launch(void* const* d_in, const int* in_sizes, int n_in,
                              void* d_out, int out_size, void* d_ws, size_t ws_size,
                              hipStream_t stream) {
  const float* x = (const float*)d_in[0];
  const float* w = (const float*)d_in[1];
  const float* t = (const float*)d_in[2];
  float* out = (float*)d_out;
  uint32_t* wb = (uint32_t*)d_ws;
  hipMemsetAsync(out, 0, (size_t)out_size * sizeof(float), stream);
  cvt_kernel<<<W_ELEMS / (256 * 8), 256, 0, stream>>>(w, wb);
  kan_gather_kernel<<<BATCH * 4, 256, 0, stream>>>(x, (const uint4*)wb, t, out);
}

// Round 5
// 90.385 us; speedup vs baseline: 1.3391x; 1.3391x over previous
//
#include <hip/hip_runtime.h>
#include <math.h>
#include <stdint.h>

#define IN_DIM  256
#define OUT_DIM 256
#define NROWS   68     // G + K
#define NT      71     // knot count
#define BATCH   512
#define W_ELEMS (NROWS * IN_DIM * OUT_DIM)   // 4,456,448
#define PART_FLOATS (4 * BATCH * OUT_DIM)    // 524,288 floats = 2 MB

// ---- Kernel A: convert w fp32 -> packed bf16 pairs ----
__device__ __forceinline__ uint32_t bf16_rne(float f) {
  uint32_t u = __builtin_bit_cast(uint32_t, f);
  return (u + 0x7fffu + ((u >> 16) & 1u)) >> 16;   // finite inputs only
}

__global__ __launch_bounds__(256) void cvt_kernel(const float* __restrict__ w,
                                                  uint32_t* __restrict__ wb) {
  const int base = (blockIdx.x * 256 + threadIdx.x) * 8;   // 8 floats / thread
  const float4 a = *(const float4*)(w + base);
  const float4 b = *(const float4*)(w + base + 4);
  uint4 o;
  o.x = bf16_rne(a.x) | (bf16_rne(a.y) << 16);
  o.y = bf16_rne(a.z) | (bf16_rne(a.w) << 16);
  o.z = bf16_rne(b.x) | (bf16_rne(b.y) << 16);
  o.w = bf16_rne(b.z) | (bf16_rne(b.w) << 16);
  *(uint4*)(wb + base / 2) = o;
}

// ---- Kernel B: gather-accumulate, bf16 weights, partial-sum stores ----
__device__ __forceinline__ void fma8(const uint4 q, const float y, float* acc) {
  acc[0] += y * __builtin_bit_cast(float, q.x << 16);
  acc[1] += y * __builtin_bit_cast(float, q.x & 0xffff0000u);
  acc[2] += y * __builtin_bit_cast(float, q.y << 16);
  acc[3] += y * __builtin_bit_cast(float, q.y & 0xffff0000u);
  acc[4] += y * __builtin_bit_cast(float, q.z << 16);
  acc[5] += y * __builtin_bit_cast(float, q.z & 0xffff0000u);
  acc[6] += y * __builtin_bit_cast(float, q.w << 16);
  acc[7] += y * __builtin_bit_cast(float, q.w & 0xffff0000u);
}

__global__ __launch_bounds__(256) void kan_gather_kernel(
    const float* __restrict__ x, const uint4* __restrict__ wp,
    const float* __restrict__ t, float* __restrict__ part) {
  __shared__ float  lt[NT];
  __shared__ float4 lyv[64];    // N0..N3 per local c
  __shared__ float  lys[64];    // silu(x) per local c
  __shared__ int    lbase[64];  // i-3 per local c
  __shared__ float  red[8 * 32 * 9];

  const int tid = threadIdx.x;
  const unsigned bid = blockIdx.x;
  // XCD-affine swizzle: slice = (xcd>>1); each slice's 2.2 MB bf16 region is
  // L2-resident on its XCD pair. b covers [0,512) per slice (bijective).
  const int sl = (bid & 7) >> 1;
  const int b  = ((bid & 1) << 8) | (bid >> 3);

  if (tid < NT) lt[tid] = t[tid];
  __syncthreads();

  // ---- Phase 1: basis for the block's 64 c's ----
  if (tid < 64) {
    const int c = sl * 64 + tid;
    const float xv = x[b * IN_DIM + c];
    int i = 3 + (int)floorf((xv + 1.0f) * 32.0f);
    i = i < 3 ? 3 : (i > 66 ? 66 : i);
    while (i > 3 && xv < lt[i]) --i;
    while (i < 66 && xv >= lt[i + 1]) ++i;

    float N0 = 1.f, N1 = 0.f, N2 = 0.f, N3 = 0.f;
    { // p = 1
      const float l1 = xv - lt[i];
      const float r1 = lt[i + 1] - xv;
      const float tp = N0 / (r1 + l1);
      N1 = l1 * tp; N0 = r1 * tp;
    }
    { // p = 2
      const float l1 = xv - lt[i];
      const float l2 = xv - lt[i - 1];
      const float r1 = lt[i + 1] - xv;
      const float r2 = lt[i + 2] - xv;
      float saved = 0.f;
      const float tp0 = N0 / (r1 + l2);
      const float n0 = saved + r1 * tp0; saved = l2 * tp0;
      const float tp1 = N1 / (r2 + l1);
      const float n1 = saved + r2 * tp1; saved = l1 * tp1;
      N0 = n0; N1 = n1; N2 = saved;
    }
    { // p = 3
      const float l1 = xv - lt[i];
      const float l2 = xv - lt[i - 1];
      const float l3 = xv - lt[i - 2];
      const float r1 = lt[i + 1] - xv;
      const float r2 = lt[i + 2] - xv;
      const float r3 = lt[i + 3] - xv;
      float saved = 0.f;
      const float tp0 = N0 / (r1 + l3);
      const float n0 = saved + r1 * tp0; saved = l3 * tp0;
      const float tp1 = N1 / (r2 + l2);
      const float n1 = saved + r2 * tp1; saved = l2 * tp1;
      const float tp2 = N2 / (r3 + l1);
      const float n2 = saved + r3 * tp2; saved = l1 * tp2;
      N0 = n0; N1 = n1; N2 = n2; N3 = saved;
    }
    lyv[tid]   = make_float4(N0, N1, N2, N3);
    lys[tid]   = xv / (1.0f + expf(-xv));
    lbase[tid] = i - 3;
  }
  __syncthreads();

  // ---- Phase 2: thread = (ol in [0,32) o-octet, cs in [0,8) -> 8 c's) ----
  const int ol = tid & 31;
  const int cs = tid >> 5;

  float acc[8] = {0.f, 0.f, 0.f, 0.f, 0.f, 0.f, 0.f, 0.f};
  const int cbeg = cs * 8;
  #pragma unroll 2
  for (int m = 0; m < 8; ++m) {
    const int cl = cbeg + m;
    const float4 yv = lyv[cl];
    const float  ys = lys[cl];
    const int base  = lbase[cl];
    const uint4* p  = wp + (size_t)(sl * 64 + cl) * 32 + ol;
    const uint4 q0 = p[(size_t)(base + 0) * 8192];
    const uint4 q1 = p[(size_t)(base + 1) * 8192];
    const uint4 q2 = p[(size_t)(base + 2) * 8192];
    const uint4 q3 = p[(size_t)(base + 3) * 8192];
    const uint4 q4 = p[(size_t)67 * 8192];
    fma8(q0, yv.x, acc);
    fma8(q1, yv.y, acc);
    fma8(q2, yv.z, acc);
    fma8(q3, yv.w, acc);
    fma8(q4, ys,   acc);
  }

  // ---- Phase 3: LDS-reduce 8 c-sub-slices, plain float4 partial store ----
  float* r = &red[(cs * 32 + ol) * 9];
  #pragma unroll
  for (int j = 0; j < 8; ++j) r[j] = acc[j];
  __syncthreads();
  if (tid < 64) {
    const int olr = tid >> 1;        // o-octet
    const int jb  = (tid & 1) * 4;   // half-octet
    float4 s = make_float4(0.f, 0.f, 0.f, 0.f);
    #pragma unroll
    for (int sI = 0; sI < 8; ++sI) {
      const float* rr = &red[(sI * 32 + olr) * 9 + jb];
      s.x += rr[0]; s.y += rr[1]; s.z += rr[2]; s.w += rr[3];
    }
    // part[sl][b][o]: element offset tid*4 == olr*8 + jb
    ((float4*)(part + ((size_t)sl * BATCH + b) * OUT_DIM))[tid] = s;
  }
}

// ---- Kernel C: reduce the 4 c-slice partials into out ----
__global__ __launch_bounds__(256) void reduce_kernel(const float* __restrict__ part,
                                                     float* __restrict__ out) {
  const int q = blockIdx.x * 256 + threadIdx.x;   // float4 index, 32768 total
  const float4* p0 = (const float4*)(part);
  const float4* p1 = (const float4*)(part + BATCH * OUT_DIM);
  const float4* p2 = (const float4*)(part + 2 * BATCH * OUT_DIM);
  const float4* p3 = (const float4*)(part + 3 * BATCH * OUT_DIM);
  const float4 a = p0[q], b = p1[q], c = p2[q], d = p3[q];
  float4 s;
  s.x = (a.x + b.x) + (c.x + d.x);
  s.y = (a.y + b.y) + (c.y + d.y);
  s.z = (a.z + b.z) + (c.z + d.z);
  s.w = (a.w + b.w) + (c.w + d.w);
  ((float4*)out)[q] = s;
}

extern "C" void kernel_launch(void* const* d_in, const int* in_sizes, int n_in,
                              void* d_out, int out_size, void* d_ws, size_t ws_size,
                              hipStream_t stream) {
  const float* x = (const float*)d_in[0];
  const float* w = (const float*)d_in[1];
  const float* t = (const float*)d_in[2];
  float* out  = (float*)d_out;
  float* part = (float*)d_ws;                       // 2 MB of partials
  uint32_t* wb = (uint32_t*)d_ws + PART_FLOATS;     // bf16 weights after
  cvt_kernel<<<W_ELEMS / (256 * 8), 256, 0, stream>>>(w, wb);
  kan_gather_kernel<<<BATCH * 4, 256, 0, stream>>>(x, (const uint4*)wb, t, part);
  reduce_kernel<<<BATCH * OUT_DIM / 4 / 256, 256, 0, stream>>>(part, out);
}